// Round 3
// baseline (218.850 us; speedup 1.0000x reference)
//
#include <hip/hip_runtime.h>
#include <math.h>

// Problem constants (from reference setup_inputs)
constexpr int CAP = 262144;   // capacity (rows of keys/values)
constexpr int NF  = 512;      // in_features == out_features

constexpr int G1  = 2048;     // k_logits blocks: 4 waves each -> 8192 waves, 32 rows/wave
constexpr int G3  = 2048;     // k_wsum blocks: 128 rows each
constexpr int G4A = 64;       // k_red blocks: 32 partial-rows each

// ---------------------------------------------------------------------------
// Kernel 1: logits[r] = -sum_f |keys[r,f] - q[f]|, plus per-block online
// softmax partials (m_b, s_b). One wave per row; lane holds 8 query floats.
// ---------------------------------------------------------------------------
__global__ __launch_bounds__(256) void k_logits(
    const float* __restrict__ q, const float* __restrict__ keys,
    float* __restrict__ logits, float* __restrict__ pm, float* __restrict__ ps)
{
    const int tid  = threadIdx.x;
    const int lane = tid & 63;
    const int wv   = tid >> 6;
    const int wgid = blockIdx.x * 4 + wv;

    const float4 q0 = *reinterpret_cast<const float4*>(q + lane * 8);
    const float4 q1 = *reinterpret_cast<const float4*>(q + lane * 8 + 4);

    float m = -INFINITY, s = 0.f;

    const int row0 = wgid * 32;
    for (int r = row0; r < row0 + 32; ++r) {
        const float* kp = keys + (size_t)r * NF + lane * 8;
        const float4 k0 = *reinterpret_cast<const float4*>(kp);
        const float4 k1 = *reinterpret_cast<const float4*>(kp + 4);
        float d = fabsf(k0.x - q0.x) + fabsf(k0.y - q0.y)
                + fabsf(k0.z - q0.z) + fabsf(k0.w - q0.w)
                + fabsf(k1.x - q1.x) + fabsf(k1.y - q1.y)
                + fabsf(k1.z - q1.z) + fabsf(k1.w - q1.w);
        #pragma unroll
        for (int off = 1; off < 64; off <<= 1) d += __shfl_xor(d, off, 64);
        const float l = -d;                 // all lanes now hold the row logit
        if (lane == 0) logits[r] = l;
        // online softmax partial (redundant but identical across lanes)
        if (l > m) { s = s * __expf(m - l) + 1.f; m = l; }
        else       { s += __expf(l - m); }
    }

    __shared__ float sm[4], ss[4];
    if (lane == 0) { sm[wv] = m; ss[wv] = s; }
    __syncthreads();
    if (tid == 0) {
        float M = sm[0], S = ss[0];
        #pragma unroll
        for (int i = 1; i < 4; ++i) {
            const float Mn = fmaxf(M, sm[i]);
            S = S * __expf(M - Mn) + ss[i] * __expf(sm[i] - Mn);
            M = Mn;
        }
        pm[blockIdx.x] = M;
        ps[blockIdx.x] = S;
    }
}

// ---------------------------------------------------------------------------
// Kernel 2: combine G1 (m,s) partials -> scal[0]=global max, scal[1]=1/S.
// Single block, fixed-order butterfly (deterministic).
// ---------------------------------------------------------------------------
__global__ __launch_bounds__(256) void k_combine(
    const float* __restrict__ pm, const float* __restrict__ ps,
    float* __restrict__ scal, int n)
{
    const int tid = threadIdx.x;
    float M = -INFINITY, S = 0.f;
    for (int i = tid; i < n; i += 256) {
        const float m2 = pm[i], s2 = ps[i];
        const float Mn = fmaxf(M, m2);
        S = S * expf(M - Mn) + s2 * expf(m2 - Mn);   // exp(-inf)=0 handles init
        M = Mn;
    }
    #pragma unroll
    for (int off = 1; off < 64; off <<= 1) {
        const float m2 = __shfl_xor(M, off, 64);
        const float s2 = __shfl_xor(S, off, 64);
        const float Mn = fmaxf(M, m2);
        S = S * expf(M - Mn) + s2 * expf(m2 - Mn);
        M = Mn;
    }
    __shared__ float sm[4], ss[4];
    const int lane = tid & 63, wv = tid >> 6;
    if (lane == 0) { sm[wv] = M; ss[wv] = S; }
    __syncthreads();
    if (tid == 0) {
        float Mg = sm[0], Sg = ss[0];
        #pragma unroll
        for (int i = 1; i < 4; ++i) {
            const float Mn = fmaxf(Mg, sm[i]);
            Sg = Sg * expf(Mg - Mn) + ss[i] * expf(sm[i] - Mn);
            Mg = Mn;
        }
        scal[0] = Mg;
        scal[1] = 1.f / Sg;
    }
}

// ---------------------------------------------------------------------------
// Kernel 3: per-block partial of out[o] = sum_r softmax[r] * values[r,o].
// 256 threads: 128 column-threads (float4 each => 512 cols) x 2 row-groups.
// ---------------------------------------------------------------------------
__global__ __launch_bounds__(256) void k_wsum(
    const float* __restrict__ values, const float* __restrict__ logits,
    const float* __restrict__ scal, float* __restrict__ part)
{
    const int tid = threadIdx.x;
    const int col = (tid & 127) * 4;
    const int rg  = tid >> 7;
    const float m    = scal[0];
    const float invS = scal[1];

    const int r0 = blockIdx.x * (CAP / G3);   // 128 rows per block
    float4 acc = {0.f, 0.f, 0.f, 0.f};
    for (int r = r0 + rg; r < r0 + (CAP / G3); r += 2) {
        const float w = __expf(logits[r] - m) * invS;
        const float4 v = *reinterpret_cast<const float4*>(values + (size_t)r * NF + col);
        acc.x += w * v.x; acc.y += w * v.y; acc.z += w * v.z; acc.w += w * v.w;
    }

    __shared__ float sp[NF];
    if (rg == 0) *reinterpret_cast<float4*>(sp + col) = acc;
    __syncthreads();
    if (rg == 1) {
        sp[col + 0] += acc.x; sp[col + 1] += acc.y;
        sp[col + 2] += acc.z; sp[col + 3] += acc.w;
    }
    __syncthreads();
    if (rg == 0)
        *reinterpret_cast<float4*>(part + (size_t)blockIdx.x * NF + col) =
            *reinterpret_cast<const float4*>(sp + col);
}

// ---------------------------------------------------------------------------
// Kernel 4a: reduce G3 partial rows -> G4A rows (32:1), parallel across blocks.
// ---------------------------------------------------------------------------
__global__ __launch_bounds__(128) void k_red(
    const float* __restrict__ part, float* __restrict__ part2)
{
    const int tid = threadIdx.x;      // 0..127
    const int col = tid * 4;
    const size_t r0 = (size_t)blockIdx.x * (G3 / G4A);
    float4 acc = {0.f, 0.f, 0.f, 0.f};
    #pragma unroll 4
    for (int j = 0; j < (G3 / G4A); ++j) {
        const float4 v = *reinterpret_cast<const float4*>(part + (r0 + j) * NF + col);
        acc.x += v.x; acc.y += v.y; acc.z += v.z; acc.w += v.w;
    }
    *reinterpret_cast<float4*>(part2 + (size_t)blockIdx.x * NF + col) = acc;
}

// ---------------------------------------------------------------------------
// Kernel 4b: reduce G4A rows -> out[512], apply sigmoid.
// ---------------------------------------------------------------------------
__global__ __launch_bounds__(256) void k_final(
    const float* __restrict__ part2, float* __restrict__ out)
{
    const int o = blockIdx.x * 256 + threadIdx.x;   // grid 2 x 256 = 512
    float acc = 0.f;
    #pragma unroll 8
    for (int j = 0; j < G4A; ++j) acc += part2[(size_t)j * NF + o];
    out[o] = 1.f / (1.f + expf(-acc));
}

// ---------------------------------------------------------------------------
extern "C" void kernel_launch(void* const* d_in, const int* in_sizes, int n_in,
                              void* d_out, int out_size, void* d_ws, size_t ws_size,
                              hipStream_t stream)
{
    const float* q    = (const float*)d_in[0];   // [512]
    const float* keys = (const float*)d_in[1];   // [262144, 512]
    const float* vals = (const float*)d_in[2];   // [262144, 512]
    float* out = (float*)d_out;                  // [512]

    // Workspace layout (floats). Total ~5.4 MB.
    float* ws     = (float*)d_ws;
    float* logits = ws;                          // CAP
    float* pm     = logits + CAP;                // G1
    float* ps     = pm + G1;                     // G1
    float* scal   = ps + G1;                     // 4 (padded for 16B alignment)
    float* part   = scal + 4;                    // G3*NF (4 MB)
    float* part2  = part + (size_t)G3 * NF;      // G4A*NF (128 KB)

    k_logits <<<G1,  256, 0, stream>>>(q, keys, logits, pm, ps);
    k_combine<<<1,   256, 0, stream>>>(pm, ps, scal, G1);
    k_wsum   <<<G3,  256, 0, stream>>>(vals, logits, scal, part);
    k_red    <<<G4A, 128, 0, stream>>>(part, part2);
    k_final  <<<2,   256, 0, stream>>>(part2, out);
}